// Round 6
// baseline (140.513 us; speedup 1.0000x reference)
//
#include <hip/hip_runtime.h>

namespace {
constexpr int XP = 264;        // f16 pixel pitch in LDS halo / x-stage
constexpr int XR = 18 * XP;    // halo row pitch
constexpr int EWP = 148;       // ew pixel pitch (floats)
constexpr int ETP = 152;       // e-tile pitch in kernel A (f16)

typedef _Float16 h2 __attribute__((ext_vector_type(2)));
typedef _Float16 h8 __attribute__((ext_vector_type(8)));
typedef float f32x4 __attribute__((ext_vector_type(4)));

__device__ __forceinline__ h2 pkrtz(float a, float b) {
  return __builtin_bit_cast(h2, __builtin_amdgcn_cvt_pkrtz(a, b));
}

#if __has_builtin(__builtin_amdgcn_fdot2)
#define HAS_FDOT2 1
#else
#define HAS_FDOT2 0
#endif

// ---- prep: W12 = W1*W2 packed in f16 B-frag order, b12 = b1*W2 + b2 ----
__global__ __launch_bounds__(256) void prep_w12(
    const float* __restrict__ W1, const float* __restrict__ b1,
    const float* __restrict__ W2, const float* __restrict__ b2,
    _Float16* __restrict__ pack, float* __restrict__ b12)
{
  __shared__ float sW1[256 * 66];
  const int t = threadIdx.x, e = blockIdx.x;
#pragma unroll
  for (int j = 0; j < 32; ++j) {
    int idx = (j * 256 + t) * 2;
    int c = idx >> 6, d = idx & 63;
    float2 v = *(const float2*)(W1 + idx);
    *(float2*)(&sW1[c * 66 + d]) = v;
  }
  __syncthreads();
  const int c = t;
  float acc = 0.f;
  for (int d = 0; d < 64; ++d)
    acc += sW1[c * 66 + d] * W2[d * 144 + e];
  // pack[((T*8+s)*64 + q*16 + n)*8 + j], c = s*32+q*8+j, e = T*16+n
  int T = e >> 4, n = e & 15;
  int s = c >> 5, q = (c >> 3) & 3, j = c & 7;
  pack[(((T * 8 + s) * 64 + q * 16 + n) << 3) + j] = (_Float16)acc;
  if (t == 0) {
    float bb = b2[e];
    for (int d = 0; d < 64; ++d) bb += b1[d] * W2[d * 144 + e];
    b12[e] = bb;
  }
}

// ---- kernel A: e[px][144] = x[px][:] * W12 + b12 via MFMA, one 64-px row/block ----
__global__ __launch_bounds__(256) void egemm(
    const float* __restrict__ x, const _Float16* __restrict__ pack,
    const float* __restrict__ b12g, _Float16* __restrict__ ebuf)
{
  __shared__ __align__(16) _Float16 xs[64 * XP];   // 33,792 B; reused as et[64*ETP]
  const int t = threadIdx.x;
  const int px0 = blockIdx.x * 64;
  const float* xrow = x + (size_t)px0 * 256;

  // stage 64 px x 256 ch fp32 -> f16
#pragma unroll
  for (int j = 0; j < 16; ++j) {
    int idx = j * 256 + t;                 // 4-float chunk id, 0..4095
    int p = idx >> 6, c4 = (idx & 63) << 2;
    float4 v = *(const float4*)(xrow + (idx << 2));
    h2 lo = pkrtz(v.x, v.y), hi = pkrtz(v.z, v.w);
    uint2 u;
    u.x = __builtin_bit_cast(unsigned, lo);
    u.y = __builtin_bit_cast(unsigned, hi);
    *(uint2*)(&xs[p * XP + c4]) = u;
  }
  __syncthreads();

  const int wave = t >> 6, lane = t & 63;
  const int q = lane >> 4, m = lane & 15;
  h8 A[8];
  const _Float16* arow = &xs[(wave * 16 + m) * XP + q * 8];
#pragma unroll
  for (int s = 0; s < 8; ++s) A[s] = *(const h8*)(arow + s * 32);
  __syncthreads();                          // all A-frags in regs; xs reusable

  _Float16* et = xs;                        // 64 x ETP e-tile
  for (int T = 0; T < 9; ++T) {
    f32x4 acc = {0.f, 0.f, 0.f, 0.f};
    const h8* bp = (const h8*)pack + (T * 8) * 64 + lane;
#pragma unroll
    for (int s = 0; s < 8; ++s)
      acc = __builtin_amdgcn_mfma_f32_16x16x32_f16(A[s], bp[s * 64], acc, 0, 0, 0);
    float bb = b12g[T * 16 + m];            // D col = lane&15
#pragma unroll
    for (int r = 0; r < 4; ++r)             // D row = q*4+r (pixel within 16)
      et[(wave * 16 + q * 4 + r) * ETP + T * 16 + m] = (_Float16)(acc[r] + bb);
  }
  __syncthreads();

  // coalesced e store: 64 rows x 18 chunks of 16B
#pragma unroll
  for (int j = 0; j < 5; ++j) {
    int idx = j * 256 + t;
    if (idx < 1152) {
      int p = idx / 18, cc = idx % 18;
      uint4 v = *(const uint4*)(&et[p * ETP + cc * 8]);
      *(uint4*)(ebuf + (size_t)(px0 + p) * 144 + cc * 8) = v;
    }
  }
}

// ---- kernel B: stage x halo + e tile, then dot2 involution ----
__global__ __launch_bounds__(256) void invo(
    const float* __restrict__ x, const _Float16* __restrict__ ebuf,
    float* __restrict__ out)
{
  __shared__ __align__(16) _Float16 xg[3 * XR];   // 28,512 B f16 halo [row][px][ch]
  __shared__ float ew[16 * EWP];                  //  9,472 B fp32 e-weights [p][144]

  const int t = threadIdx.x;
  const int blk = blockIdx.x;               // (b*64 + h)*4 + strip
  const int strip = blk & 3;
  const int bh = blk >> 2;
  const int h = bh & 63;
  const int b = bh >> 6;
  const int w0 = strip * 16;
  const int pix0 = ((b << 6) + h) * 64 + w0;

  // stage 3 halo rows x 18 px x 256 ch, fp32 -> f16, zero OOB
  for (int idx = t; idx < 3 * 18 * 64; idx += 256) {
    int c4 = (idx & 63) << 2;
    int pr = idx >> 6;                      // 0..53
    int r = (pr >= 36) ? 2 : (pr >= 18 ? 1 : 0);
    int j = pr - r * 18;
    int hh = h + r - 1, ww = w0 + j - 1;
    float4 v = make_float4(0.f, 0.f, 0.f, 0.f);
    if (((unsigned)hh < 64u) && ((unsigned)ww < 64u))
      v = *(const float4*)(x + ((((b << 6) + hh) << 6) + ww) * 256 + c4);
    h2 lo = pkrtz(v.x, v.y), hi = pkrtz(v.z, v.w);
    uint2 u;
    u.x = __builtin_bit_cast(unsigned, lo);
    u.y = __builtin_bit_cast(unsigned, hi);
    *(uint2*)(&xg[r * XR + j * XP + c4]) = u;
  }
  // stage e tile: 16 px x 144 f16 -> fp32 LDS (288 chunks of 16B)
  for (int idx = t; idx < 288; idx += 256) {
    int p = idx / 18, cc = idx % 18;
    uint4 v = *(const uint4*)(ebuf + (size_t)(pix0 + p) * 144 + cc * 8);
    h2 e0 = __builtin_bit_cast(h2, v.x), e1 = __builtin_bit_cast(h2, v.y);
    h2 e2 = __builtin_bit_cast(h2, v.z), e3 = __builtin_bit_cast(h2, v.w);
    float* dst = &ew[p * EWP + cc * 8];
    *(float4*)(dst + 0) = make_float4((float)e0[0], (float)e0[1], (float)e1[0], (float)e1[1]);
    *(float4*)(dst + 4) = make_float4((float)e2[0], (float)e2[1], (float)e3[0], (float)e3[1]);
  }
  __syncthreads();

  // involution: thread=(p,g); 18x ds_read_b128, v_dot2_f32_f16 inner
  {
    const int p = t >> 4, g = t & 15;
    float ewr[9];
#pragma unroll
    for (int k = 0; k < 9; ++k) ewr[k] = ew[p * EWP + g * 9 + k];
    h2 wp[8];
#pragma unroll
    for (int m = 0; m < 8; ++m)
      wp[m] = pkrtz(ewr[m], ewr[m + 1]);
    const float w8 = ewr[8], wb0 = ewr[0];
    const int g144 = g * 144;
    const int pbase = p * XP;
    float res[16];
#pragma unroll
    for (int gc = 0; gc < 16; ++gc) res[gc] = 0.f;
#pragma unroll
    for (int j = 0; j < 18; ++j) {
      int f = g144 + j * 8;
      int tap = f >> 8;                     // constant within the 8-chunk
      int ch = f & 255;
      int di = (tap * 86) >> 8;             // tap/3
      int dj = tap - 3 * di;
      uint4 dv = *(const uint4*)(&xg[di * XR + (p + dj) * XP + ch]);
      h2 v[4];
      v[0] = __builtin_bit_cast(h2, dv.x);
      v[1] = __builtin_bit_cast(h2, dv.y);
      v[2] = __builtin_bit_cast(h2, dv.z);
      v[3] = __builtin_bit_cast(h2, dv.w);
#pragma unroll
      for (int i = 0; i < 4; ++i) {
        const int u = j * 8 + 2 * i;        // compile-time
        const int m = u % 9;
        if (m == 8) {                       // pair crosses gc boundary
          res[u / 9]     += (float)v[i][0] * w8;
          res[u / 9 + 1] += (float)v[i][1] * wb0;
        } else {
#if HAS_FDOT2
          res[u / 9] = __builtin_amdgcn_fdot2(v[i], wp[m], res[u / 9], false);
#else
          res[u / 9] += (float)v[i][0] * ewr[m] + (float)v[i][1] * ewr[m + 1];
#endif
        }
      }
    }
    float* orow = out + (size_t)(pix0 + p) * 256 + (g << 4);
    *(float4*)(orow + 0)  = make_float4(res[0],  res[1],  res[2],  res[3]);
    *(float4*)(orow + 4)  = make_float4(res[4],  res[5],  res[6],  res[7]);
    *(float4*)(orow + 8)  = make_float4(res[8],  res[9],  res[10], res[11]);
    *(float4*)(orow + 12) = make_float4(res[12], res[13], res[14], res[15]);
  }
}

// ---- fallback: R5 fused kernel (used only if ws_size too small for ebuf) ----
__global__ __launch_bounds__(256) void invo_fused(
    const float* __restrict__ x, const _Float16* __restrict__ pack,
    const float* __restrict__ b12g, float* __restrict__ out)
{
  __shared__ __align__(16) _Float16 xg[3 * XR];
  __shared__ float ew[16 * EWP];
  const int t = threadIdx.x;
  const int blk = blockIdx.x;
  const int strip = blk & 3;
  const int bh = blk >> 2;
  const int h = bh & 63;
  const int b = bh >> 6;
  const int w0 = strip * 16;
  for (int idx = t; idx < 3 * 18 * 64; idx += 256) {
    int c4 = (idx & 63) << 2;
    int pr = idx >> 6;
    int r = (pr >= 36) ? 2 : (pr >= 18 ? 1 : 0);
    int j = pr - r * 18;
    int hh = h + r - 1, ww = w0 + j - 1;
    float4 v = make_float4(0.f, 0.f, 0.f, 0.f);
    if (((unsigned)hh < 64u) && ((unsigned)ww < 64u))
      v = *(const float4*)(x + ((((b << 6) + hh) << 6) + ww) * 256 + c4);
    h2 lo = pkrtz(v.x, v.y), hi = pkrtz(v.z, v.w);
    uint2 u;
    u.x = __builtin_bit_cast(unsigned, lo);
    u.y = __builtin_bit_cast(unsigned, hi);
    *(uint2*)(&xg[r * XR + j * XP + c4]) = u;
  }
  __syncthreads();
  {
    const int wave = t >> 6, lane = t & 63;
    const int q = lane >> 4, m = lane & 15;
    h8 A[8];
    const _Float16* arow = &xg[XR + (m + 1) * XP + q * 8];
#pragma unroll
    for (int s = 0; s < 8; ++s) A[s] = *(const h8*)(arow + s * 32);
    for (int T = wave; T < 9; T += 4) {
      f32x4 acc = {0.f, 0.f, 0.f, 0.f};
      const h8* bp = (const h8*)pack + (T * 8) * 64 + lane;
#pragma unroll
      for (int s = 0; s < 8; ++s)
        acc = __builtin_amdgcn_mfma_f32_16x16x32_f16(A[s], bp[s * 64], acc, 0, 0, 0);
      float bb = b12g[T * 16 + m];
#pragma unroll
      for (int r = 0; r < 4; ++r)
        ew[(q * 4 + r) * EWP + T * 16 + m] = acc[r] + bb;
    }
  }
  __syncthreads();
  {
    const int p = t >> 4, g = t & 15;
    float ewr[9];
#pragma unroll
    for (int k = 0; k < 9; ++k) ewr[k] = ew[p * EWP + g * 9 + k];
    h2 wp[8];
#pragma unroll
    for (int m = 0; m < 8; ++m) wp[m] = pkrtz(ewr[m], ewr[m + 1]);
    const float w8 = ewr[8], wb0 = ewr[0];
    const int g144 = g * 144;
    const int pbase = p * XP;
    float res[16];
#pragma unroll
    for (int gc = 0; gc < 16; ++gc) res[gc] = 0.f;
#pragma unroll
    for (int j = 0; j < 18; ++j) {
      int f = g144 + j * 8;
      int tap = f >> 8;
      int ch = f & 255;
      int di = (tap * 86) >> 8;
      int dj = tap - 3 * di;
      uint4 dv = *(const uint4*)(&xg[di * XR + (p + dj) * XP + ch]);
      h2 v[4];
      v[0] = __builtin_bit_cast(h2, dv.x);
      v[1] = __builtin_bit_cast(h2, dv.y);
      v[2] = __builtin_bit_cast(h2, dv.z);
      v[3] = __builtin_bit_cast(h2, dv.w);
#pragma unroll
      for (int i = 0; i < 4; ++i) {
        const int u = j * 8 + 2 * i;
        const int m = u % 9;
        if (m == 8) {
          res[u / 9]     += (float)v[i][0] * w8;
          res[u / 9 + 1] += (float)v[i][1] * wb0;
        } else {
#if HAS_FDOT2
          res[u / 9] = __builtin_amdgcn_fdot2(v[i], wp[m], res[u / 9], false);
#else
          res[u / 9] += (float)v[i][0] * ewr[m] + (float)v[i][1] * ewr[m + 1];
#endif
        }
      }
    }
    float* orow = out + (size_t)(((((b << 6) + h) << 6) + w0 + p)) * 256 + (g << 4);
    *(float4*)(orow + 0)  = make_float4(res[0],  res[1],  res[2],  res[3]);
    *(float4*)(orow + 4)  = make_float4(res[4],  res[5],  res[6],  res[7]);
    *(float4*)(orow + 8)  = make_float4(res[8],  res[9],  res[10], res[11]);
    *(float4*)(orow + 12) = make_float4(res[12], res[13], res[14], res[15]);
  }
}
} // namespace

extern "C" void kernel_launch(void* const* d_in, const int* in_sizes, int n_in,
                              void* d_out, int out_size, void* d_ws, size_t ws_size,
                              hipStream_t stream) {
  const float* x  = (const float*)d_in[0];
  const float* W1 = (const float*)d_in[1];
  const float* b1 = (const float*)d_in[2];
  const float* W2 = (const float*)d_in[3];
  const float* b2 = (const float*)d_in[4];
  float* out = (float*)d_out;
  _Float16* pack = (_Float16*)d_ws;                        // 73,728 B
  float* b12 = (float*)((char*)d_ws + 73728);              // 576 B
  const size_t EOFF = 131072;
  const size_t ENEED = EOFF + (size_t)32768 * 144 * 2;     // ~9.57 MB
  prep_w12<<<144, 256, 0, stream>>>(W1, b1, W2, b2, pack, b12);
  if (ws_size >= ENEED) {
    _Float16* ebuf = (_Float16*)((char*)d_ws + EOFF);
    egemm<<<512, 256, 0, stream>>>(x, pack, b12, ebuf);
    invo<<<2048, 256, 0, stream>>>(x, ebuf, out);
  } else {
    invo_fused<<<2048, 256, 0, stream>>>(x, pack, b12, out);
  }
}

// Round 7
// 114.465 us; speedup vs baseline: 1.2276x; 1.2276x over previous
//
#include <hip/hip_runtime.h>

namespace {
constexpr int XP = 264;        // f16 pixel pitch in LDS halo
constexpr int XR = 18 * XP;    // halo row pitch
constexpr int EWP = 148;       // ew pixel pitch (floats)

typedef _Float16 h2 __attribute__((ext_vector_type(2)));
typedef _Float16 h8 __attribute__((ext_vector_type(8)));
typedef float f32x4 __attribute__((ext_vector_type(4)));

__device__ __forceinline__ h2 pkrtz(float a, float b) {
  return __builtin_bit_cast(h2, __builtin_amdgcn_cvt_pkrtz(a, b));
}

#if __has_builtin(__builtin_amdgcn_fdot2)
#define HAS_FDOT2 1
#else
#define HAS_FDOT2 0
#endif

// ---- prep v2: W12 = W1*W2 packed in f16 B-frag order, b12 = b1*W2 + b2 ----
// 10 blocks: blocks 0..8 = one 16-e tile each (thread = c); block 9 = bias.
__global__ __launch_bounds__(256) void prep_w12(
    const float* __restrict__ W1, const float* __restrict__ b1,
    const float* __restrict__ W2, const float* __restrict__ b2,
    _Float16* __restrict__ pack, float* __restrict__ b12)
{
  const int t = threadIdx.x;
  const int T = blockIdx.x;
  if (T < 9) {
    __shared__ float sw2[64 * 16];          // W2 tile [d][n], 4 KB
    for (int i = t; i < 1024; i += 256) {
      int d = i >> 4, n = i & 15;
      sw2[i] = W2[d * 144 + T * 16 + n];
    }
    __syncthreads();
    const int c = t;
    float acc[16];
#pragma unroll
    for (int n = 0; n < 16; ++n) acc[n] = 0.f;
    for (int d = 0; d < 64; d += 4) {
      float4 w1 = *(const float4*)(W1 + c * 64 + d);
#pragma unroll
      for (int dd = 0; dd < 4; ++dd) {
        float a = (dd == 0) ? w1.x : (dd == 1) ? w1.y : (dd == 2) ? w1.z : w1.w;
        const float* r = &sw2[(d + dd) * 16];
#pragma unroll
        for (int n = 0; n < 16; ++n) acc[n] += a * r[n];   // LDS broadcast
      }
    }
    // pack[((T*8+s)*64 + q*16 + n)*8 + j], c = s*32+q*8+j
    int s = c >> 5, q = (c >> 3) & 3, j = c & 7;
#pragma unroll
    for (int n = 0; n < 16; ++n)
      pack[(((T * 8 + s) * 64 + q * 16 + n) << 3) + j] = (_Float16)acc[n];
  } else if (t < 144) {
    float bb = b2[t];
    for (int d = 0; d < 64; ++d) bb += b1[d] * W2[d * 144 + t];  // coalesced over e
    b12[t] = bb;
  }
}

// ---- fused: f16 halo stage -> f16 MFMA GEMM -> dot2 involution ----
__global__ __launch_bounds__(256) void invo_fused(
    const float* __restrict__ x,
    const _Float16* __restrict__ pack,
    const float* __restrict__ b12g,
    float* __restrict__ out)
{
  __shared__ __align__(16) _Float16 xg[3 * XR];   // 28,512 B f16 halo [row][px][ch]
  __shared__ float ew[16 * EWP];                  //  9,472 B fp32 e-weights [p][144]

  const int t = threadIdx.x;
  // XCD-aware swizzle: consecutive blockIdx round-robin across 8 XCDs -> pin image b to XCD.
  const int blk = blockIdx.x;
  const int b = blk & 7;
  const int r_ = blk >> 3;
  const int strip = r_ & 3;
  const int h = r_ >> 2;
  const int w0 = strip * 16;
  const int pix0 = ((b << 6) + h) * 64 + w0;

  // ---- stage 3 halo rows x 18 px x 256 ch, fp32 -> f16 (packed cvt), zero OOB ----
  for (int idx = t; idx < 3 * 18 * 64; idx += 256) {
    int c4 = (idx & 63) << 2;
    int pr = idx >> 6;                      // 0..53
    int r = (pr >= 36) ? 2 : (pr >= 18 ? 1 : 0);
    int j = pr - r * 18;
    int hh = h + r - 1, ww = w0 + j - 1;
    float4 v = make_float4(0.f, 0.f, 0.f, 0.f);
    if (((unsigned)hh < 64u) && ((unsigned)ww < 64u))
      v = *(const float4*)(x + ((((b << 6) + hh) << 6) + ww) * 256 + c4);
    h2 lo = pkrtz(v.x, v.y), hi = pkrtz(v.z, v.w);
    uint2 u;
    u.x = __builtin_bit_cast(unsigned, lo);
    u.y = __builtin_bit_cast(unsigned, hi);
    *(uint2*)(&xg[r * XR + j * XP + c4]) = u;
  }
  __syncthreads();

  // ---- GEMM via MFMA: e[p][e] = b12[e] + sum_c x[p][c] * W12[c][e] ----
  {
    const int wave = t >> 6, lane = t & 63;
    const int q = lane >> 4, m = lane & 15;
    h8 A[8];
    const _Float16* arow = &xg[XR + (m + 1) * XP + q * 8];
#pragma unroll
    for (int s = 0; s < 8; ++s)
      A[s] = *(const h8*)(arow + s * 32);
    for (int T = wave; T < 9; T += 4) {
      f32x4 acc = {0.f, 0.f, 0.f, 0.f};
      const h8* bp = (const h8*)pack + (T * 8) * 64 + lane;
#pragma unroll
      for (int s = 0; s < 8; ++s)
        acc = __builtin_amdgcn_mfma_f32_16x16x32_f16(A[s], bp[s * 64], acc, 0, 0, 0);
      float bb = b12g[T * 16 + m];            // D col = lane&15
#pragma unroll
      for (int r = 0; r < 4; ++r)
        ew[(q * 4 + r) * EWP + T * 16 + m] = acc[r] + bb;   // D row = q*4+r = pixel
    }
  }
  __syncthreads();

  // ---- involution: thread=(p,g); 18x ds_read_b128, v_dot2_f32_f16 inner ----
  {
    const int p = t >> 4, g = t & 15;
    float ewr[9];
#pragma unroll
    for (int k = 0; k < 9; ++k) ewr[k] = ew[p * EWP + g * 9 + k];
    h2 wp[8];
#pragma unroll
    for (int m = 0; m < 8; ++m)
      wp[m] = pkrtz(ewr[m], ewr[m + 1]);
    const float w8 = ewr[8], wb0 = ewr[0];
    const int g144 = g * 144;
    const int pbase = p * XP;
    float res[16];
#pragma unroll
    for (int gc = 0; gc < 16; ++gc) res[gc] = 0.f;
#pragma unroll
    for (int j = 0; j < 18; ++j) {
      int f = g144 + j * 8;
      int tap = f >> 8;                     // constant within the 8-chunk
      int ch = f & 255;
      int di = (tap * 86) >> 8;             // tap/3
      int dj = tap - 3 * di;
      uint4 dv = *(const uint4*)(&xg[di * XR + (p + dj) * XP + ch]);
      h2 v[4];
      v[0] = __builtin_bit_cast(h2, dv.x);
      v[1] = __builtin_bit_cast(h2, dv.y);
      v[2] = __builtin_bit_cast(h2, dv.z);
      v[3] = __builtin_bit_cast(h2, dv.w);
#pragma unroll
      for (int i = 0; i < 4; ++i) {
        const int u = j * 8 + 2 * i;        // compile-time
        const int m = u % 9;
        if (m == 8) {                       // pair crosses gc boundary
          res[u / 9]     += (float)v[i][0] * w8;
          res[u / 9 + 1] += (float)v[i][1] * wb0;
        } else {
#if HAS_FDOT2
          res[u / 9] = __builtin_amdgcn_fdot2(v[i], wp[m], res[u / 9], false);
#else
          res[u / 9] += (float)v[i][0] * ewr[m] + (float)v[i][1] * ewr[m + 1];
#endif
        }
      }
    }
    float* orow = out + (size_t)(pix0 + p) * 256 + (g << 4);
    *(float4*)(orow + 0)  = make_float4(res[0],  res[1],  res[2],  res[3]);
    *(float4*)(orow + 4)  = make_float4(res[4],  res[5],  res[6],  res[7]);
    *(float4*)(orow + 8)  = make_float4(res[8],  res[9],  res[10], res[11]);
    *(float4*)(orow + 12) = make_float4(res[12], res[13], res[14], res[15]);
  }
}
} // namespace

extern "C" void kernel_launch(void* const* d_in, const int* in_sizes, int n_in,
                              void* d_out, int out_size, void* d_ws, size_t ws_size,
                              hipStream_t stream) {
  const float* x  = (const float*)d_in[0];
  const float* W1 = (const float*)d_in[1];
  const float* b1 = (const float*)d_in[2];
  const float* W2 = (const float*)d_in[3];
  const float* b2 = (const float*)d_in[4];
  float* out = (float*)d_out;
  _Float16* pack = (_Float16*)d_ws;                        // 73,728 B
  float* b12 = (float*)((char*)d_ws + 73728);              // 576 B
  prep_w12<<<10, 256, 0, stream>>>(W1, b1, W2, b2, pack, b12);
  invo_fused<<<2048, 256, 0, stream>>>(x, pack, b12, out);
}